// Round 8
// baseline (471.897 us; speedup 1.0000x reference)
//
#include <hip/hip_runtime.h>

// DCNv2 v11 = v7 main kernel (exact revert to last clean pass, 124.5us)
//           + probe B: coalesced-gather A/B measurement (10 reps).
// v10 (coalesced gather + ds_bpermute) failed twice with ambiguous infra
// signatures; this round tests the TA-transaction model with zero
// correctness risk: probe B == round-4 probe A except lane->address map
// (pixel=lane>>2, chunk=lane&3 vs pixel=lane&15, chunk=lane>>4). Same
// instruction count, same LDS/occupancy. r4 probe A measured 783us;
// TA model predicts probe B ~200-350us (4x fewer line-transactions).

#define NI 8
#define CI 128
#define HI 96
#define WI 96
#define CO 128
#define K2 9
#define P_TOT 9216
#define TP 64
#define NTILE 144                                   // 24 ty * 6 tx
#define CPAD 40
#define XT_ELEMS ((size_t)NI * P_TOT * CI)          // 9,437,184 bf16
#define WT_ELEMS ((size_t)K2 * CO * CI)             // 147,456 bf16
#define WS_NEED ((XT_ELEMS + WT_ELEMS) * 2)

typedef short short8 __attribute__((ext_vector_type(8)));
typedef float f32x4 __attribute__((ext_vector_type(4)));

static __device__ __forceinline__ ushort bf16_rne(float x) {
    unsigned u = __float_as_uint(x);
    u = (u + 0x7FFF + ((u >> 16) & 1)) >> 16;
    return (ushort)u;
}
static __device__ __forceinline__ unsigned pack_bf2(float a, float b) {
    return (unsigned)bf16_rne(a) | ((unsigned)bf16_rne(b) << 16);
}
static __device__ __forceinline__ unsigned cvt_pk_bf16(float a, float b) {
    unsigned r;
    asm("v_cvt_pk_bf16_f32 %0, %1, %2" : "=v"(r) : "v"(a), "v"(b));
    return r;
}
static __device__ __forceinline__ float bflo(unsigned u) { return __uint_as_float(u << 16); }
static __device__ __forceinline__ float bfhi(unsigned u) { return __uint_as_float(u & 0xFFFF0000u); }

union U4S8 { uint4 u; short8 s; };

// async global->LDS, 16B per lane; LDS dest = wave-uniform base + lane*16
static __device__ __forceinline__ void gll16(const ushort* g, ushort* l) {
    __builtin_amdgcn_global_load_lds(
        (const __attribute__((address_space(1))) unsigned int*)g,
        (__attribute__((address_space(3))) unsigned int*)l, 16, 0, 0);
}

// ---- pre-kernel: grid = 2304 (x transpose) + 72 (weight recast+swizzle) ----
__global__ __launch_bounds__(256)
void pre_kernel(const float* __restrict__ x, const float* __restrict__ w,
                ushort* __restrict__ xt, ushort* __restrict__ wt) {
    const int bid = blockIdx.x;
    const int tid = threadIdx.x;
    if (bid < 2304) {
        // transpose x[n][c][hw] fp32 -> xt[n][hw][c] bf16; tile 64c x 64hw
        __shared__ ushort t[64][68];
        const int n = bid / 288, rr = bid % 288;
        const int cblk = rr & 1, hw0 = (rr >> 1) * 64;
        #pragma unroll
        for (int j = 0; j < 4; ++j) {
            int item = j * 256 + tid;               // < 1024
            int c = item >> 4, q = item & 15;
            float4 f = *(const float4*)(x + ((size_t)(n * CI + cblk * 64 + c)) * P_TOT
                                        + hw0 + q * 4);
            t[q * 4 + 0][c] = bf16_rne(f.x);
            t[q * 4 + 1][c] = bf16_rne(f.y);
            t[q * 4 + 2][c] = bf16_rne(f.z);
            t[q * 4 + 3][c] = bf16_rne(f.w);
        }
        __syncthreads();
        #pragma unroll
        for (int j = 0; j < 4; ++j) {
            int item = j * 256 + tid;               // < 1024
            int row = item >> 4, seg = item & 15;
            uint2 v = *(const uint2*)&t[row][seg * 4];
            *(uint2*)(xt + ((size_t)n * P_TOT + hw0 + row) * CI + cblk * 64 + seg * 4) = v;
        }
    } else {
        // wt swizzled for LDS: slot s = k*2048 + o*16 + csw holds 8 ch of
        // c-seg cs = csw ^ (o&7); DMA's linear fill gives swizzled layout.
        int s = (bid - 2304) * 256 + tid;           // < 18432
        int k   = s >> 11;
        int r2  = s & 2047;
        int o   = r2 >> 4;
        int csw = r2 & 15;
        int cs  = csw ^ (o & 7);
        const float* src = w + (size_t)o * (CI * K2) + cs * 8 * K2 + k;
        ushort tmp[8];
        #pragma unroll
        for (int j = 0; j < 8; ++j) tmp[j] = bf16_rne(src[j * K2]);
        *(uint4*)&wt[(size_t)s * 8] = *(uint4*)tmp;
    }
}

__global__ __launch_bounds__(256, 2)
void dcn_mfma4_kernel(const ushort* __restrict__ xt,
                      const ushort* __restrict__ wt,
                      const float* __restrict__ offset,
                      const float* __restrict__ mask,
                      const float* __restrict__ bias,
                      float* __restrict__ out)
{
    __shared__ uint2  s_midx[K2 * TP];       // packed corner row indices
    __shared__ float4 s_mw[K2 * TP];         // bilinear*mask weights
    __shared__ ushort s_w[2][CO * CI];       // dbuf tap slab, swizzled, 2x32KB

    const int tid  = threadIdx.x;
    const int bid  = blockIdx.x;
    const int n    = bid & 7;                // XCD swizzle (n per XCD)
    const int tile = bid >> 3;               // 0..143
    const int ty   = tile / 6;               // 0..23 -> y0 = ty*4
    const int tx   = tile - ty * 6;          // 0..5  -> x0 = tx*16
    const int wave = tid >> 6;
    const int lane = tid & 63;
    const int l15  = lane & 15;
    const int quad = lane >> 4;

    auto stage = [&](int k, int buf) {
        const ushort* g = wt + ((size_t)k * 2048 + wave * 512) * 8;
        ushort* l = &s_w[buf][wave * 512 * 8];
        #pragma unroll
        for (int i = 0; i < 8; ++i)
            gll16(g + (size_t)(i * 64 + lane) * 8, l + i * 64 * 8);
    };

    stage(0, 0);        // tap 0 in flight under meta phase

    // ---- meta phase (pixel i -> (iy,ix) within the 4x16 tile) ----
    for (int itm = 0; itm < 3; ++itm) {
        int item = itm * 256 + tid;          // k*TP + i, < 576
        if (item < K2 * TP) {
            int k = item / TP;
            int i = item % TP;
            int iy = i >> 4, ix = i & 15;
            int ph = ty * 4 + iy;
            int pw = tx * 16 + ix;
            int p  = ph * WI + pw;
            float offy = offset[((size_t)n * (2 * K2) + 2 * k    ) * P_TOT + p];
            float offx = offset[((size_t)n * (2 * K2) + 2 * k + 1) * P_TOT + p];
            float m    = mask  [((size_t)n * K2 + k) * P_TOT + p];
            int ky = k / 3, kx = k % 3;
            float py = (float)(ph - 1 + ky) + offy;
            float px = (float)(pw - 1 + kx) + offx;
            float y0f = floorf(py), x0f = floorf(px);
            float wy = py - y0f, wx = px - x0f;
            int y0 = (int)y0f, x0 = (int)x0f;
            int y1 = y0 + 1,  x1 = x0 + 1;
            bool vy0 = (y0 >= 0) && (y0 < HI);
            bool vy1 = (y1 >= 0) && (y1 < HI);
            bool vx0 = (x0 >= 0) && (x0 < WI);
            bool vx1 = (x1 >= 0) && (x1 < WI);
            unsigned i00 = (vy0 && vx0) ? (unsigned)(y0 * WI + x0) : 0u;
            unsigned i01 = (vy0 && vx1) ? (unsigned)(y0 * WI + x1) : 0u;
            unsigned i10 = (vy1 && vx0) ? (unsigned)(y1 * WI + x0) : 0u;
            unsigned i11 = (vy1 && vx1) ? (unsigned)(y1 * WI + x1) : 0u;
            float w00 = (vy0 && vx0) ? (1.f - wy) * (1.f - wx) * m : 0.f;
            float w01 = (vy0 && vx1) ? (1.f - wy) * wx          * m : 0.f;
            float w10 = (vy1 && vx0) ? wy * (1.f - wx)          * m : 0.f;
            float w11 = (vy1 && vx1) ? wy * wx                  * m : 0.f;
            s_midx[item] = make_uint2(i00 | (i01 << 16), i10 | (i11 << 16));
            s_mw[item]   = make_float4(w00, w01, w10, w11);
        }
    }
    __syncthreads();    // meta visible + tap0 slab landed (vmcnt drained)

    f32x4 acc[8];
    #pragma unroll
    for (int a = 0; a < 8; ++a) acc[a] = (f32x4){0.f, 0.f, 0.f, 0.f};

    const ushort* xb = xt + (size_t)n * (P_TOT * CI) + quad * 8;

    for (int k = 0; k < K2; ++k) {
        const int buf = k & 1;

        uint2  mi = s_midx[k * TP + wave * 16 + l15];
        float4 mw = s_mw[k * TP + wave * 16 + l15];
        const ushort* c00 = xb + (size_t)(mi.x & 0xFFFF) * CI;
        const ushort* c01 = xb + (size_t)(mi.x >> 16)    * CI;
        const ushort* c10 = xb + (size_t)(mi.y & 0xFFFF) * CI;
        const ushort* c11 = xb + (size_t)(mi.y >> 16)    * CI;

        // ALL 16 gather loads first, THEN the stage DMA (vmcnt in-order:
        // bilinear's waits on gathers leave the stage loads in flight).
        uint4 g0[4], g1[4], g2[4], g3[4];
        #pragma unroll
        for (int cb = 0; cb < 4; ++cb) {
            g0[cb] = *(const uint4*)(c00 + cb * 32);
            g1[cb] = *(const uint4*)(c01 + cb * 32);
            g2[cb] = *(const uint4*)(c10 + cb * 32);
            g3[cb] = *(const uint4*)(c11 + cb * 32);
        }

        if (k < 8) stage(k + 1, buf ^ 1);   // async, lands before next tap

        #pragma unroll
        for (int cb = 0; cb < 4; ++cb) {
            uint4 r0 = g0[cb], r1 = g1[cb], r2 = g2[cb], r3 = g3[cb];
            float v0 = mw.x * bflo(r0.x) + mw.y * bflo(r1.x) + mw.z * bflo(r2.x) + mw.w * bflo(r3.x);
            float v1 = mw.x * bfhi(r0.x) + mw.y * bfhi(r1.x) + mw.z * bfhi(r2.x) + mw.w * bfhi(r3.x);
            float v2 = mw.x * bflo(r0.y) + mw.y * bflo(r1.y) + mw.z * bflo(r2.y) + mw.w * bflo(r3.y);
            float v3 = mw.x * bfhi(r0.y) + mw.y * bfhi(r1.y) + mw.z * bfhi(r2.y) + mw.w * bfhi(r3.y);
            float v4 = mw.x * bflo(r0.z) + mw.y * bflo(r1.z) + mw.z * bflo(r2.z) + mw.w * bflo(r3.z);
            float v5 = mw.x * bfhi(r0.z) + mw.y * bfhi(r1.z) + mw.z * bfhi(r2.z) + mw.w * bfhi(r3.z);
            float v6 = mw.x * bflo(r0.w) + mw.y * bflo(r1.w) + mw.z * bflo(r2.w) + mw.w * bflo(r3.w);
            float v7 = mw.x * bfhi(r0.w) + mw.y * bfhi(r1.w) + mw.z * bfhi(r2.w) + mw.w * bfhi(r3.w);
            U4S8 cvt;
            cvt.u.x = cvt_pk_bf16(v0, v1);
            cvt.u.y = cvt_pk_bf16(v2, v3);
            cvt.u.z = cvt_pk_bf16(v4, v5);
            cvt.u.w = cvt_pk_bf16(v6, v7);
            short8 bfr = cvt.s;
            __builtin_amdgcn_s_setprio(1);
            #pragma unroll
            for (int ot = 0; ot < 8; ++ot) {
                int o = ot * 16 + l15;
                short8 afr = *(const short8*)&s_w[buf][o * CI + (((cb * 4 + quad) ^ (o & 7)) * 8)];
                acc[ot] = __builtin_amdgcn_mfma_f32_16x16x32_bf16(afr, bfr, acc[ot], 0, 0, 0);
            }
            __builtin_amdgcn_s_setprio(0);
        }
        __syncthreads();    // waves done with buf; next slab landed (vmcnt)
    }

    // ---- epilogue (wave = iy row of the 4x16 tile, l15 = ix) ----
    const int pbase = (ty * 4 + wave) * WI + tx * 16 + l15;
    #pragma unroll
    for (int ot = 0; ot < 8; ++ot) {
        #pragma unroll
        for (int r = 0; r < 4; ++r) {
            int o = ot * 16 + quad * 4 + r;
            out[((size_t)n * CO + o) * P_TOT + pbase] = acc[ot][r] + bias[o];
        }
    }
}

// ---- PROBE B: coalesced-arrangement gather, measurement only, 10 reps. ----
// Identical to round-4 probe A except the lane->address map:
//   A (r4, 783us): pixel = lane&15, chunk = lane>>4  -> 64 line-trans/load
//   B (this):      pixel = lane>>2, chunk = lane&3   -> 16 line-trans/load
// Same instruction count, same LDS footprint, same occupancy. Results
// consumed lane-locally (no permute needed; discarded via keep-alives).
#define PROBE_REPS 10
__global__ __launch_bounds__(256, 2)
void probe_gather_co(const ushort* __restrict__ xt,
                     const float* __restrict__ offset,
                     const float* __restrict__ mask)
{
    __shared__ uint2  s_midx[K2 * TP];
    __shared__ float4 s_mw[K2 * TP];
    __shared__ ushort s_w[2][CO * CI];       // occupancy fidelity (unread)

    const int tid  = threadIdx.x;
    const int bid  = blockIdx.x;
    const int n    = bid & 7;
    const int tile = bid >> 3;
    const int ty   = tile / 6;
    const int tx   = tile - ty * 6;
    const int wave = tid >> 6;
    const int lane = tid & 63;
    const int gp   = lane >> 2;              // pixel
    const int gq   = lane & 3;               // 16B chunk

    ((volatile ushort*)s_w)[tid] = (ushort)tid;   // keep LDS allocated

    for (int it = 0; it < 3; ++it) {
        int item = it * 256 + tid;
        if (item < K2 * TP) {
            int k = item / TP;
            int i = item % TP;
            int iy = i >> 4, ix = i & 15;
            int ph = ty * 4 + iy;
            int pw = tx * 16 + ix;
            int p  = ph * WI + pw;
            float offy = offset[((size_t)n * (2 * K2) + 2 * k    ) * P_TOT + p];
            float offx = offset[((size_t)n * (2 * K2) + 2 * k + 1) * P_TOT + p];
            float m    = mask  [((size_t)n * K2 + k) * P_TOT + p];
            int ky = k / 3, kx = k % 3;
            float py = (float)(ph - 1 + ky) + offy;
            float px = (float)(pw - 1 + kx) + offx;
            float y0f = floorf(py), x0f = floorf(px);
            float wy = py - y0f, wx = px - x0f;
            int y0 = (int)y0f, x0 = (int)x0f;
            int y1 = y0 + 1,  x1 = x0 + 1;
            bool vy0 = (y0 >= 0) && (y0 < HI);
            bool vy1 = (y1 >= 0) && (y1 < HI);
            bool vx0 = (x0 >= 0) && (x0 < WI);
            bool vx1 = (x1 >= 0) && (x1 < WI);
            unsigned i00 = (vy0 && vx0) ? (unsigned)(y0 * WI + x0) : 0u;
            unsigned i01 = (vy0 && vx1) ? (unsigned)(y0 * WI + x1) : 0u;
            unsigned i10 = (vy1 && vx0) ? (unsigned)(y1 * WI + x0) : 0u;
            unsigned i11 = (vy1 && vx1) ? (unsigned)(y1 * WI + x1) : 0u;
            float w00 = (vy0 && vx0) ? (1.f - wy) * (1.f - wx) * m : 0.f;
            float w01 = (vy0 && vx1) ? (1.f - wy) * wx          * m : 0.f;
            float w10 = (vy1 && vx0) ? wy * (1.f - wx)          * m : 0.f;
            float w11 = (vy1 && vx1) ? wy * wx                  * m : 0.f;
            s_midx[item] = make_uint2(i00 | (i01 << 16), i10 | (i11 << 16));
            s_mw[item]   = make_float4(w00, w01, w10, w11);
        }
    }
    __syncthreads();

    f32x4 acc[8];
    #pragma unroll
    for (int a = 0; a < 8; ++a) acc[a] = (f32x4){0.f, 0.f, 0.f, 0.f};

    // coalesced base: chunk gq of each 256B pixel row
    const ushort* xbg = xt + (size_t)n * (P_TOT * CI) + gq * 8;
    const int mrow_g = wave * 16 + gp;

    for (int rep = 0; rep < PROBE_REPS; ++rep) {
        unsigned lo = 0;
        asm volatile("" : "+v"(lo));        // launder: defeat load hoisting
        const ushort* xbr = xbg + lo;
        for (int k = 0; k < K2; ++k) {
            uint2  mi = s_midx[k * TP + mrow_g];
            float4 mw = s_mw[k * TP + mrow_g];
            const ushort* c00 = xbr + (size_t)(mi.x & 0xFFFF) * CI;
            const ushort* c01 = xbr + (size_t)(mi.x >> 16)    * CI;
            const ushort* c10 = xbr + (size_t)(mi.y & 0xFFFF) * CI;
            const ushort* c11 = xbr + (size_t)(mi.y >> 16)    * CI;

            uint4 g0[4], g1[4], g2[4], g3[4];
            #pragma unroll
            for (int cb = 0; cb < 4; ++cb) {
                g0[cb] = *(const uint4*)(c00 + cb * 32);
                g1[cb] = *(const uint4*)(c01 + cb * 32);
                g2[cb] = *(const uint4*)(c10 + cb * 32);
                g3[cb] = *(const uint4*)(c11 + cb * 32);
            }

            #pragma unroll
            for (int cb = 0; cb < 4; ++cb) {
                uint4 r0 = g0[cb], r1 = g1[cb], r2 = g2[cb], r3 = g3[cb];
                float v0 = mw.x * bflo(r0.x) + mw.y * bflo(r1.x) + mw.z * bflo(r2.x) + mw.w * bflo(r3.x);
                float v1 = mw.x * bfhi(r0.x) + mw.y * bfhi(r1.x) + mw.z * bfhi(r2.x) + mw.w * bfhi(r3.x);
                float v2 = mw.x * bflo(r0.y) + mw.y * bflo(r1.y) + mw.z * bflo(r2.y) + mw.w * bflo(r3.y);
                float v3 = mw.x * bfhi(r0.y) + mw.y * bfhi(r1.y) + mw.z * bfhi(r2.y) + mw.w * bfhi(r3.y);
                float v4 = mw.x * bflo(r0.z) + mw.y * bflo(r1.z) + mw.z * bflo(r2.z) + mw.w * bflo(r3.z);
                float v5 = mw.x * bfhi(r0.z) + mw.y * bfhi(r1.z) + mw.z * bfhi(r2.z) + mw.w * bfhi(r3.z);
                float v6 = mw.x * bflo(r0.w) + mw.y * bflo(r1.w) + mw.z * bflo(r2.w) + mw.w * bflo(r3.w);
                float v7 = mw.x * bfhi(r0.w) + mw.y * bfhi(r1.w) + mw.z * bfhi(r2.w) + mw.w * bfhi(r3.w);
                U4S8 cvt;
                cvt.u.x = cvt_pk_bf16(v0, v1);
                cvt.u.y = cvt_pk_bf16(v2, v3);
                cvt.u.z = cvt_pk_bf16(v4, v5);
                cvt.u.w = cvt_pk_bf16(v6, v7);
                acc[cb][0] += __uint_as_float(cvt.u.x);
                acc[cb][1] += __uint_as_float(cvt.u.y);
                acc[cb][2] += __uint_as_float(cvt.u.z);
                acc[cb][3] += __uint_as_float(cvt.u.w);
                acc[cb + 4][0] += __uint_as_float(cvt.u.w);
                acc[cb + 4][1] += __uint_as_float(cvt.u.x);
                acc[cb + 4][2] += __uint_as_float(cvt.u.y);
                acc[cb + 4][3] += __uint_as_float(cvt.u.z);
            }
        }
    }

    #pragma unroll
    for (int a = 0; a < 8; ++a)
        asm volatile("" :: "v"(acc[a][0]), "v"(acc[a][1]),
                           "v"(acc[a][2]), "v"(acc[a][3]));
}

// ---------------- fallback (no workspace): round-2 structure ----------------
__global__ __launch_bounds__(256, 3)
void dcn_fallback_kernel(const float* __restrict__ x,
                         const float* __restrict__ offset,
                         const float* __restrict__ mask,
                         const float* __restrict__ weight,
                         const float* __restrict__ bias,
                         float* __restrict__ out)
{
    __shared__ uint2  s_midx[K2 * TP];
    __shared__ float4 s_mw[K2 * TP];
    __shared__ ushort s_v[TP * CPAD];
    __shared__ ushort s_w[CO * CPAD];

    const int tid  = threadIdx.x;
    const int bid  = blockIdx.x;
    const int n    = bid & 7;
    const int p0   = (bid >> 3) * TP;

    for (int it = 0; it < 3; ++it) {
        int item = it * 256 + tid;
        if (item < K2 * TP) {
            int k = item / TP;
            int i = item % TP;
            int p  = p0 + i;
            int ph = p / WI;
            int pw = p % WI;
            float offy = offset[((size_t)n * (2 * K2) + 2 * k    ) * P_TOT + p];
            float offx = offset[((size_t)n * (2 * K2) + 2 * k + 1) * P_TOT + p];
            float m    = mask  [((size_t)n * K2 + k) * P_TOT + p];
            int ky = k / 3, kx = k % 3;
            float py = (float)(ph - 1 + ky) + offy;
            float px = (float)(pw - 1 + kx) + offx;
            float y0f = floorf(py), x0f = floorf(px);
            float wy = py - y0f, wx = px - x0f;
            int y0 = (int)y0f, x0 = (int)x0f;
            int y1 = y0 + 1,  x1 = x0 + 1;
            bool vy0 = (y0 >= 0) && (y0 < HI);
            bool vy1 = (y1 >= 0) && (y1 < HI);
            bool vx0 = (x0 >= 0) && (x0 < WI);
            bool vx1 = (x1 >= 0) && (x1 < WI);
            unsigned i00 = (vy0 && vx0) ? (unsigned)(y0 * WI + x0) : 0u;
            unsigned i01 = (vy0 && vx1) ? (unsigned)(y0 * WI + x1) : 0u;
            unsigned i10 = (vy1 && vx0) ? (unsigned)(y1 * WI + x0) : 0u;
            unsigned i11 = (vy1 && vx1) ? (unsigned)(y1 * WI + x1) : 0u;
            float w00 = (vy0 && vx0) ? (1.f - wy) * (1.f - wx) * m : 0.f;
            float w01 = (vy0 && vx1) ? (1.f - wy) * wx          * m : 0.f;
            float w10 = (vy1 && vx0) ? wy * (1.f - wx)          * m : 0.f;
            float w11 = (vy1 && vx1) ? wy * wx                  * m : 0.f;
            s_midx[item] = make_uint2(i00 | (i01 << 16), i10 | (i11 << 16));
            s_mw[item]   = make_float4(w00, w01, w10, w11);
        }
    }
    __syncthreads();

    const int wave = tid >> 6;
    const int lane = tid & 63;
    const int l15  = lane & 15;
    const int quad = lane >> 4;
    const int o_base = (wave >> 1) * 64;
    const int p_base = (wave & 1) * 32;
    const int gp = tid & 63;
    const int cg = wave;

    f32x4 acc[4][2];
    #pragma unroll
    for (int a = 0; a < 4; ++a)
        #pragma unroll
        for (int b = 0; b < 2; ++b) acc[a][b] = (f32x4){0.f, 0.f, 0.f, 0.f};

    for (int cb = 0; cb < 4; ++cb) {
        for (int k = 0; k < K2; ++k) {
            {
                uint2  mi = s_midx[k * TP + gp];
                float4 mw = s_mw[k * TP + gp];
                int i00 = mi.x & 0xFFFF, i01 = mi.x >> 16;
                int i10 = mi.y & 0xFFFF, i11 = mi.y >> 16;
                const float* xb = x + ((size_t)(n * CI + cb * 32 + cg * 8)) * (HI * WI);
                float v[8];
                #pragma unroll
                for (int j = 0; j < 8; ++j) {
                    const float* xp = xb + (size_t)j * (HI * WI);
                    v[j] = mw.x * xp[i00] + mw.y * xp[i01]
                         + mw.z * xp[i10] + mw.w * xp[i11];
                }
                uint4 pk;
                pk.x = pack_bf2(v[0], v[1]);
                pk.y = pack_bf2(v[2], v[3]);
                pk.z = pack_bf2(v[4], v[5]);
                pk.w = pack_bf2(v[6], v[7]);
                *(uint4*)&s_v[gp * CPAD + cg * 8] = pk;
            }
            {
                int o = tid >> 1, half = tid & 1;
                const float* wsrc = weight + (size_t)o * (CI * K2)
                                  + (cb * 32 + half * 16) * K2 + k;
                ushort tmp[16];
                #pragma unroll
                for (int i = 0; i < 16; ++i) tmp[i] = bf16_rne(wsrc[i * K2]);
                *(uint4*)&s_w[o * CPAD + half * 16]     = *(uint4*)&tmp[0];
                *(uint4*)&s_w[o * CPAD + half * 16 + 8] = *(uint4*)&tmp[8];
            }
            __syncthreads();
            short8 afr[4], bfr[2];
            #pragma unroll
            for (int ot = 0; ot < 4; ++ot)
                afr[ot] = *(const short8*)&s_w[(o_base + ot * 16 + l15) * CPAD + quad * 8];
            #pragma unroll
            for (int pt = 0; pt < 2; ++pt)
                bfr[pt] = *(const short8*)&s_v[(p_base + pt * 16 + l15) * CPAD + quad * 8];
            #pragma unroll
            for (int ot = 0; ot < 4; ++ot)
                #pragma unroll
                for (int pt = 0; pt < 2; ++pt)
                    acc[ot][pt] = __builtin_amdgcn_mfma_f32_16x16x32_bf16(
                        afr[ot], bfr[pt], acc[ot][pt], 0, 0, 0);
            __syncthreads();
        }
    }

    #pragma unroll
    for (int ot = 0; ot < 4; ++ot)
        #pragma unroll
        for (int r = 0; r < 4; ++r) {
            int o = o_base + ot * 16 + quad * 4 + r;
            float b = bias[o];
            #pragma unroll
            for (int pt = 0; pt < 2; ++pt) {
                int p = p0 + p_base + pt * 16 + l15;
                out[((size_t)n * CO + o) * P_TOT + p] = acc[ot][pt][r] + b;
            }
        }
}

extern "C" void kernel_launch(void* const* d_in, const int* in_sizes, int n_in,
                              void* d_out, int out_size, void* d_ws, size_t ws_size,
                              hipStream_t stream) {
    const float* x      = (const float*)d_in[0];
    const float* offset = (const float*)d_in[1];
    const float* mask   = (const float*)d_in[2];
    const float* weight = (const float*)d_in[3];
    const float* bias   = (const float*)d_in[4];
    float* out = (float*)d_out;

    dim3 block(256);
    if (ws_size >= WS_NEED) {
        ushort* xt = (ushort*)d_ws;
        ushort* wt = xt + XT_ELEMS;
        pre_kernel<<<dim3(2304 + 72), block, 0, stream>>>(x, weight, xt, wt);
        dcn_mfma4_kernel<<<dim3(NI * NTILE), block, 0, stream>>>(
            xt, wt, offset, mask, bias, out);
        // measurement probe (writes nothing; timing read from rocprof table)
        probe_gather_co<<<dim3(NI * NTILE), block, 0, stream>>>(xt, offset, mask);
    } else {
        dcn_fallback_kernel<<<dim3(NI * NTILE), block, 0, stream>>>(
            x, offset, mask, weight, bias, out);
    }
}

// Round 9
// 168.224 us; speedup vs baseline: 2.8052x; 2.8052x over previous
//
#include <hip/hip_runtime.h>

// DCNv2 fused v10 (3rd attempt) = v7 + coalesced gather + ds_bpermute repack.
// Round-8 A/B probe CONFIRMED the TA-transaction model: identical probe,
// lane map (pixel=lane&15,chunk=lane>>4) -> 783us vs (pixel=lane>>2,
// chunk=lane&3) -> 316us (2.5x), VALUBusy 31->82% (VALU-bound once
// transactions fixed). This kernel applies the winning arrangement:
// gather coalesced (16-lane group = 4 pixel rows x 4 contiguous 16B = 4
// line-transactions vs 16), bilinear+pack lane-local, then 4 ds_bpermute
// per cb (fixed perm g(l)=(l&15)*4+(l>>4); verified: src pixel g>>2=l&15,
// src chunk g&3=l>>4) restore the MFMA B-frag layout. Weights: v7's
// LDS-DMA staging, stage issued AFTER the tap's gathers (vmcnt in-order).
// Prior v10 submissions failed on infra-sick nodes (r6 container-fail;
// r7 core dump w/ 341s push). Probe B passed cleanly with the same
// gather addresses, so the addressing is HW-proven.

#define NI 8
#define CI 128
#define HI 96
#define WI 96
#define CO 128
#define K2 9
#define P_TOT 9216
#define TP 64
#define NTILE 144                                   // 24 ty * 6 tx
#define CPAD 40
#define XT_ELEMS ((size_t)NI * P_TOT * CI)          // 9,437,184 bf16
#define WT_ELEMS ((size_t)K2 * CO * CI)             // 147,456 bf16
#define WS_NEED ((XT_ELEMS + WT_ELEMS) * 2)

typedef short short8 __attribute__((ext_vector_type(8)));
typedef float f32x4 __attribute__((ext_vector_type(4)));

static __device__ __forceinline__ ushort bf16_rne(float x) {
    unsigned u = __float_as_uint(x);
    u = (u + 0x7FFF + ((u >> 16) & 1)) >> 16;
    return (ushort)u;
}
static __device__ __forceinline__ unsigned pack_bf2(float a, float b) {
    return (unsigned)bf16_rne(a) | ((unsigned)bf16_rne(b) << 16);
}
static __device__ __forceinline__ unsigned cvt_pk_bf16(float a, float b) {
    unsigned r;
    asm("v_cvt_pk_bf16_f32 %0, %1, %2" : "=v"(r) : "v"(a), "v"(b));
    return r;
}
static __device__ __forceinline__ float bflo(unsigned u) { return __uint_as_float(u << 16); }
static __device__ __forceinline__ float bfhi(unsigned u) { return __uint_as_float(u & 0xFFFF0000u); }

union U4S8 { uint4 u; short8 s; };

// async global->LDS, 16B per lane; LDS dest = wave-uniform base + lane*16
static __device__ __forceinline__ void gll16(const ushort* g, ushort* l) {
    __builtin_amdgcn_global_load_lds(
        (const __attribute__((address_space(1))) unsigned int*)g,
        (__attribute__((address_space(3))) unsigned int*)l, 16, 0, 0);
}

// ---- pre-kernel: grid = 2304 (x transpose) + 72 (weight recast+swizzle) ----
__global__ __launch_bounds__(256)
void pre_kernel(const float* __restrict__ x, const float* __restrict__ w,
                ushort* __restrict__ xt, ushort* __restrict__ wt) {
    const int bid = blockIdx.x;
    const int tid = threadIdx.x;
    if (bid < 2304) {
        // transpose x[n][c][hw] fp32 -> xt[n][hw][c] bf16; tile 64c x 64hw
        __shared__ ushort t[64][68];
        const int n = bid / 288, rr = bid % 288;
        const int cblk = rr & 1, hw0 = (rr >> 1) * 64;
        #pragma unroll
        for (int j = 0; j < 4; ++j) {
            int item = j * 256 + tid;               // < 1024
            int c = item >> 4, q = item & 15;
            float4 f = *(const float4*)(x + ((size_t)(n * CI + cblk * 64 + c)) * P_TOT
                                        + hw0 + q * 4);
            t[q * 4 + 0][c] = bf16_rne(f.x);
            t[q * 4 + 1][c] = bf16_rne(f.y);
            t[q * 4 + 2][c] = bf16_rne(f.z);
            t[q * 4 + 3][c] = bf16_rne(f.w);
        }
        __syncthreads();
        #pragma unroll
        for (int j = 0; j < 4; ++j) {
            int item = j * 256 + tid;               // < 1024
            int row = item >> 4, seg = item & 15;
            uint2 v = *(const uint2*)&t[row][seg * 4];
            *(uint2*)(xt + ((size_t)n * P_TOT + hw0 + row) * CI + cblk * 64 + seg * 4) = v;
        }
    } else {
        // wt swizzled for LDS: slot s = k*2048 + o*16 + csw holds 8 ch of
        // c-seg cs = csw ^ (o&7); DMA's linear fill gives swizzled layout.
        int s = (bid - 2304) * 256 + tid;           // < 18432
        int k   = s >> 11;
        int r2  = s & 2047;
        int o   = r2 >> 4;
        int csw = r2 & 15;
        int cs  = csw ^ (o & 7);
        const float* src = w + (size_t)o * (CI * K2) + cs * 8 * K2 + k;
        ushort tmp[8];
        #pragma unroll
        for (int j = 0; j < 8; ++j) tmp[j] = bf16_rne(src[j * K2]);
        *(uint4*)&wt[(size_t)s * 8] = *(uint4*)tmp;
    }
}

__global__ __launch_bounds__(256, 2)
void dcn_mfma4_kernel(const ushort* __restrict__ xt,
                      const ushort* __restrict__ wt,
                      const float* __restrict__ offset,
                      const float* __restrict__ mask,
                      const float* __restrict__ bias,
                      float* __restrict__ out)
{
    __shared__ uint2  s_midx[K2 * TP];       // packed corner row indices
    __shared__ float4 s_mw[K2 * TP];         // bilinear*mask weights
    __shared__ ushort s_w[2][CO * CI];       // dbuf tap slab, swizzled, 2x32KB

    const int tid  = threadIdx.x;
    const int bid  = blockIdx.x;
    const int n    = bid & 7;                // XCD swizzle (n per XCD)
    const int tile = bid >> 3;               // 0..143
    const int ty   = tile / 6;               // 0..23 -> y0 = ty*4
    const int tx   = tile - ty * 6;          // 0..5  -> x0 = tx*16
    const int wave = tid >> 6;
    const int lane = tid & 63;
    const int l15  = lane & 15;
    const int quad = lane >> 4;
    // gather arrangement: pixel = lane>>2, 16B chunk = lane&3
    const int gp   = lane >> 2;
    const int gq   = lane & 3;
    // bpermute src lane for MFMA B-layout: g(l) = (l&15)*4 + (l>>4)
    const int permaddr = (l15 * 4 + quad) * 4;

    auto stage = [&](int k, int buf) {
        const ushort* g = wt + ((size_t)k * 2048 + wave * 512) * 8;
        ushort* l = &s_w[buf][wave * 512 * 8];
        #pragma unroll
        for (int i = 0; i < 8; ++i)
            gll16(g + (size_t)(i * 64 + lane) * 8, l + i * 64 * 8);
    };

    stage(0, 0);        // tap 0 in flight under meta phase

    // ---- meta phase (pixel i -> (iy,ix) within the 4x16 tile) ----
    for (int itm = 0; itm < 3; ++itm) {
        int item = itm * 256 + tid;          // k*TP + i, < 576
        if (item < K2 * TP) {
            int k = item / TP;
            int i = item % TP;
            int iy = i >> 4, ix = i & 15;
            int ph = ty * 4 + iy;
            int pw = tx * 16 + ix;
            int p  = ph * WI + pw;
            float offy = offset[((size_t)n * (2 * K2) + 2 * k    ) * P_TOT + p];
            float offx = offset[((size_t)n * (2 * K2) + 2 * k + 1) * P_TOT + p];
            float m    = mask  [((size_t)n * K2 + k) * P_TOT + p];
            int ky = k / 3, kx = k % 3;
            float py = (float)(ph - 1 + ky) + offy;
            float px = (float)(pw - 1 + kx) + offx;
            float y0f = floorf(py), x0f = floorf(px);
            float wy = py - y0f, wx = px - x0f;
            int y0 = (int)y0f, x0 = (int)x0f;
            int y1 = y0 + 1,  x1 = x0 + 1;
            bool vy0 = (y0 >= 0) && (y0 < HI);
            bool vy1 = (y1 >= 0) && (y1 < HI);
            bool vx0 = (x0 >= 0) && (x0 < WI);
            bool vx1 = (x1 >= 0) && (x1 < WI);
            unsigned i00 = (vy0 && vx0) ? (unsigned)(y0 * WI + x0) : 0u;
            unsigned i01 = (vy0 && vx1) ? (unsigned)(y0 * WI + x1) : 0u;
            unsigned i10 = (vy1 && vx0) ? (unsigned)(y1 * WI + x0) : 0u;
            unsigned i11 = (vy1 && vx1) ? (unsigned)(y1 * WI + x1) : 0u;
            float w00 = (vy0 && vx0) ? (1.f - wy) * (1.f - wx) * m : 0.f;
            float w01 = (vy0 && vx1) ? (1.f - wy) * wx          * m : 0.f;
            float w10 = (vy1 && vx0) ? wy * (1.f - wx)          * m : 0.f;
            float w11 = (vy1 && vx1) ? wy * wx                  * m : 0.f;
            s_midx[item] = make_uint2(i00 | (i01 << 16), i10 | (i11 << 16));
            s_mw[item]   = make_float4(w00, w01, w10, w11);
        }
    }
    __syncthreads();    // meta visible + tap0 slab landed (vmcnt drained)

    f32x4 acc[8];
    #pragma unroll
    for (int a = 0; a < 8; ++a) acc[a] = (f32x4){0.f, 0.f, 0.f, 0.f};

    // gather base: chunk gq of each 256B pixel row
    const ushort* xbg = xt + (size_t)n * (P_TOT * CI) + gq * 8;
    const int mrow_g = wave * 16 + gp;

    for (int k = 0; k < K2; ++k) {
        const int buf = k & 1;

        uint2  mi = s_midx[k * TP + mrow_g];
        float4 mw = s_mw[k * TP + mrow_g];
        const ushort* c00 = xbg + (size_t)(mi.x & 0xFFFF) * CI;
        const ushort* c01 = xbg + (size_t)(mi.x >> 16)    * CI;
        const ushort* c10 = xbg + (size_t)(mi.y & 0xFFFF) * CI;
        const ushort* c11 = xbg + (size_t)(mi.y >> 16)    * CI;

        // 16 gather loads: 16-lane group = 4 pixel rows x 4 contiguous 16B
        // chunks -> 4 line-transactions/group (was 16). Issued before the
        // stage DMA so bilinear's vmcnt waits leave the stage in flight.
        uint4 g0[4], g1[4], g2[4], g3[4];
        #pragma unroll
        for (int cb = 0; cb < 4; ++cb) {
            g0[cb] = *(const uint4*)(c00 + cb * 32);
            g1[cb] = *(const uint4*)(c01 + cb * 32);
            g2[cb] = *(const uint4*)(c10 + cb * 32);
            g3[cb] = *(const uint4*)(c11 + cb * 32);
        }

        if (k < 8) stage(k + 1, buf ^ 1);   // async, lands before next tap

        #pragma unroll
        for (int cb = 0; cb < 4; ++cb) {
            uint4 r0 = g0[cb], r1 = g1[cb], r2 = g2[cb], r3 = g3[cb];
            // bilinear, lane-local in gather order: this lane = pixel gp,
            // channels cb*32 + gq*8 .. +7
            float v0 = mw.x * bflo(r0.x) + mw.y * bflo(r1.x) + mw.z * bflo(r2.x) + mw.w * bflo(r3.x);
            float v1 = mw.x * bfhi(r0.x) + mw.y * bfhi(r1.x) + mw.z * bfhi(r2.x) + mw.w * bfhi(r3.x);
            float v2 = mw.x * bflo(r0.y) + mw.y * bflo(r1.y) + mw.z * bflo(r2.y) + mw.w * bflo(r3.y);
            float v3 = mw.x * bfhi(r0.y) + mw.y * bfhi(r1.y) + mw.z * bfhi(r2.y) + mw.w * bfhi(r3.y);
            float v4 = mw.x * bflo(r0.z) + mw.y * bflo(r1.z) + mw.z * bflo(r2.z) + mw.w * bflo(r3.z);
            float v5 = mw.x * bfhi(r0.z) + mw.y * bfhi(r1.z) + mw.z * bfhi(r2.z) + mw.w * bfhi(r3.z);
            float v6 = mw.x * bflo(r0.w) + mw.y * bflo(r1.w) + mw.z * bflo(r2.w) + mw.w * bflo(r3.w);
            float v7 = mw.x * bfhi(r0.w) + mw.y * bfhi(r1.w) + mw.z * bfhi(r2.w) + mw.w * bfhi(r3.w);
            // pack, then permute packed dwords into MFMA B-frag layout:
            // dst lane l <- src lane (l&15)*4 + (l>>4)
            unsigned d0 = cvt_pk_bf16(v0, v1);
            unsigned d1 = cvt_pk_bf16(v2, v3);
            unsigned d2 = cvt_pk_bf16(v4, v5);
            unsigned d3 = cvt_pk_bf16(v6, v7);
            U4S8 cvt;
            cvt.u.x = (unsigned)__builtin_amdgcn_ds_bpermute(permaddr, (int)d0);
            cvt.u.y = (unsigned)__builtin_amdgcn_ds_bpermute(permaddr, (int)d1);
            cvt.u.z = (unsigned)__builtin_amdgcn_ds_bpermute(permaddr, (int)d2);
            cvt.u.w = (unsigned)__builtin_amdgcn_ds_bpermute(permaddr, (int)d3);
            short8 bfr = cvt.s;
            __builtin_amdgcn_s_setprio(1);
            #pragma unroll
            for (int ot = 0; ot < 8; ++ot) {
                int o = ot * 16 + l15;
                short8 afr = *(const short8*)&s_w[buf][o * CI + (((cb * 4 + quad) ^ (o & 7)) * 8)];
                acc[ot] = __builtin_amdgcn_mfma_f32_16x16x32_bf16(afr, bfr, acc[ot], 0, 0, 0);
            }
            __builtin_amdgcn_s_setprio(0);
        }
        __syncthreads();    // waves done with buf; next slab landed (vmcnt)
    }

    // ---- epilogue (wave = iy row of the 4x16 tile, l15 = ix) ----
    const int pbase = (ty * 4 + wave) * WI + tx * 16 + l15;
    #pragma unroll
    for (int ot = 0; ot < 8; ++ot) {
        #pragma unroll
        for (int r = 0; r < 4; ++r) {
            int o = ot * 16 + quad * 4 + r;
            out[((size_t)n * CO + o) * P_TOT + pbase] = acc[ot][r] + bias[o];
        }
    }
}

// ---------------- fallback (no workspace): round-2 structure ----------------
__global__ __launch_bounds__(256, 3)
void dcn_fallback_kernel(const float* __restrict__ x,
                         const float* __restrict__ offset,
                         const float* __restrict__ mask,
                         const float* __restrict__ weight,
                         const float* __restrict__ bias,
                         float* __restrict__ out)
{
    __shared__ uint2  s_midx[K2 * TP];
    __shared__ float4 s_mw[K2 * TP];
    __shared__ ushort s_v[TP * CPAD];
    __shared__ ushort s_w[CO * CPAD];

    const int tid  = threadIdx.x;
    const int bid  = blockIdx.x;
    const int n    = bid & 7;
    const int p0   = (bid >> 3) * TP;

    for (int it = 0; it < 3; ++it) {
        int item = it * 256 + tid;
        if (item < K2 * TP) {
            int k = item / TP;
            int i = item % TP;
            int p  = p0 + i;
            int ph = p / WI;
            int pw = p % WI;
            float offy = offset[((size_t)n * (2 * K2) + 2 * k    ) * P_TOT + p];
            float offx = offset[((size_t)n * (2 * K2) + 2 * k + 1) * P_TOT + p];
            float m    = mask  [((size_t)n * K2 + k) * P_TOT + p];
            int ky = k / 3, kx = k % 3;
            float py = (float)(ph - 1 + ky) + offy;
            float px = (float)(pw - 1 + kx) + offx;
            float y0f = floorf(py), x0f = floorf(px);
            float wy = py - y0f, wx = px - x0f;
            int y0 = (int)y0f, x0 = (int)x0f;
            int y1 = y0 + 1,  x1 = x0 + 1;
            bool vy0 = (y0 >= 0) && (y0 < HI);
            bool vy1 = (y1 >= 0) && (y1 < HI);
            bool vx0 = (x0 >= 0) && (x0 < WI);
            bool vx1 = (x1 >= 0) && (x1 < WI);
            unsigned i00 = (vy0 && vx0) ? (unsigned)(y0 * WI + x0) : 0u;
            unsigned i01 = (vy0 && vx1) ? (unsigned)(y0 * WI + x1) : 0u;
            unsigned i10 = (vy1 && vx0) ? (unsigned)(y1 * WI + x0) : 0u;
            unsigned i11 = (vy1 && vx1) ? (unsigned)(y1 * WI + x1) : 0u;
            float w00 = (vy0 && vx0) ? (1.f - wy) * (1.f - wx) * m : 0.f;
            float w01 = (vy0 && vx1) ? (1.f - wy) * wx          * m : 0.f;
            float w10 = (vy1 && vx0) ? wy * (1.f - wx)          * m : 0.f;
            float w11 = (vy1 && vx1) ? wy * wx                  * m : 0.f;
            s_midx[item] = make_uint2(i00 | (i01 << 16), i10 | (i11 << 16));
            s_mw[item]   = make_float4(w00, w01, w10, w11);
        }
    }
    __syncthreads();

    const int wave = tid >> 6;
    const int lane = tid & 63;
    const int l15  = lane & 15;
    const int quad = lane >> 4;
    const int o_base = (wave >> 1) * 64;
    const int p_base = (wave & 1) * 32;
    const int gp = tid & 63;
    const int cg = wave;

    f32x4 acc[4][2];
    #pragma unroll
    for (int a = 0; a < 4; ++a)
        #pragma unroll
        for (int b = 0; b < 2; ++b) acc[a][b] = (f32x4){0.f, 0.f, 0.f, 0.f};

    for (int cb = 0; cb < 4; ++cb) {
        for (int k = 0; k < K2; ++k) {
            {
                uint2  mi = s_midx[k * TP + gp];
                float4 mw = s_mw[k * TP + gp];
                int i00 = mi.x & 0xFFFF, i01 = mi.x >> 16;
                int i10 = mi.y & 0xFFFF, i11 = mi.y >> 16;
                const float* xb = x + ((size_t)(n * CI + cb * 32 + cg * 8)) * (HI * WI);
                float v[8];
                #pragma unroll
                for (int j = 0; j < 8; ++j) {
                    const float* xp = xb + (size_t)j * (HI * WI);
                    v[j] = mw.x * xp[i00] + mw.y * xp[i01]
                         + mw.z * xp[i10] + mw.w * xp[i11];
                }
                uint4 pk;
                pk.x = pack_bf2(v[0], v[1]);
                pk.y = pack_bf2(v[2], v[3]);
                pk.z = pack_bf2(v[4], v[5]);
                pk.w = pack_bf2(v[6], v[7]);
                *(uint4*)&s_v[gp * CPAD + cg * 8] = pk;
            }
            {
                int o = tid >> 1, half = tid & 1;
                const float* wsrc = weight + (size_t)o * (CI * K2)
                                  + (cb * 32 + half * 16) * K2 + k;
                ushort tmp[16];
                #pragma unroll
                for (int i = 0; i < 16; ++i) tmp[i] = bf16_rne(wsrc[i * K2]);
                *(uint4*)&s_w[o * CPAD + half * 16]     = *(uint4*)&tmp[0];
                *(uint4*)&s_w[o * CPAD + half * 16 + 8] = *(uint4*)&tmp[8];
            }
            __syncthreads();
            short8 afr[4], bfr[2];
            #pragma unroll
            for (int ot = 0; ot < 4; ++ot)
                afr[ot] = *(const short8*)&s_w[(o_base + ot * 16 + l15) * CPAD + quad * 8];
            #pragma unroll
            for (int pt = 0; pt < 2; ++pt)
                bfr[pt] = *(const short8*)&s_v[(p_base + pt * 16 + l15) * CPAD + quad * 8];
            #pragma unroll
            for (int ot = 0; ot < 4; ++ot)
                #pragma unroll
                for (int pt = 0; pt < 2; ++pt)
                    acc[ot][pt] = __builtin_amdgcn_mfma_f32_16x16x32_bf16(
                        afr[ot], bfr[pt], acc[ot][pt], 0, 0, 0);
            __syncthreads();
        }
    }

    #pragma unroll
    for (int ot = 0; ot < 4; ++ot)
        #pragma unroll
        for (int r = 0; r < 4; ++r) {
            int o = o_base + ot * 16 + quad * 4 + r;
            float b = bias[o];
            #pragma unroll
            for (int pt = 0; pt < 2; ++pt) {
                int p = p0 + p_base + pt * 16 + l15;
                out[((size_t)n * CO + o) * P_TOT + p] = acc[ot][pt][r] + b;
            }
        }
}

extern "C" void kernel_launch(void* const* d_in, const int* in_sizes, int n_in,
                              void* d_out, int out_size, void* d_ws, size_t ws_size,
                              hipStream_t stream) {
    const float* x      = (const float*)d_in[0];
    const float* offset = (const float*)d_in[1];
    const float* mask   = (const float*)d_in[2];
    const float* weight = (const float*)d_in[3];
    const float* bias   = (const float*)d_in[4];
    float* out = (float*)d_out;

    dim3 block(256);
    if (ws_size >= WS_NEED) {
        ushort* xt = (ushort*)d_ws;
        ushort* wt = xt + XT_ELEMS;
        pre_kernel<<<dim3(2304 + 72), block, 0, stream>>>(x, weight, xt, wt);
        dcn_mfma4_kernel<<<dim3(NI * NTILE), block, 0, stream>>>(
            xt, wt, offset, mask, bias, out);
    } else {
        dcn_fallback_kernel<<<dim3(NI * NTILE), block, 0, stream>>>(
            x, offset, mask, weight, bias, out);
    }
}

// Round 10
// 165.813 us; speedup vs baseline: 2.8460x; 1.0145x over previous
//
#include <hip/hip_runtime.h>

// DCNv2 fused v12 = v10 + 1-tap-ahead gather prefetch + counted-vmcnt
// barriers (T3/T4). v10 (coalesced gather + bpermute) measured 83us with
// VALUBusy 35% / MfmaUtil 10.7% -> ~40% idle = per-tap exposed L2 latency
// + vmcnt(0) barrier drains. v12 unrolls taps 2x (named regsets A/B):
// issue stage(k+1) then NEXT tap's 16 gathers, compute current tap,
// then `s_waitcnt vmcnt(16)` + raw s_barrier -- drains only the 8 stage
// DMAs (oldest), leaves the 16 prefetched gathers in flight across the
// barrier. Ledger (steady state): enter half with <=16 outstanding (own
// gathers); +8 stage +16 next-gathers = 40; consume waits vmcnt(24);
// barrier waits vmcnt(16). LDS-read hazard safe: afr ds_reads drain via
// lgkm before their MFMAs, so all waves' reads of s_w[buf] complete
// before they arrive at the barrier that precedes the buf overwrite.

#define NI 8
#define CI 128
#define HI 96
#define WI 96
#define CO 128
#define K2 9
#define P_TOT 9216
#define TP 64
#define NTILE 144                                   // 24 ty * 6 tx
#define CPAD 40
#define XT_ELEMS ((size_t)NI * P_TOT * CI)          // 9,437,184 bf16
#define WT_ELEMS ((size_t)K2 * CO * CI)             // 147,456 bf16
#define WS_NEED ((XT_ELEMS + WT_ELEMS) * 2)

typedef short short8 __attribute__((ext_vector_type(8)));
typedef float f32x4 __attribute__((ext_vector_type(4)));

static __device__ __forceinline__ ushort bf16_rne(float x) {
    unsigned u = __float_as_uint(x);
    u = (u + 0x7FFF + ((u >> 16) & 1)) >> 16;
    return (ushort)u;
}
static __device__ __forceinline__ unsigned pack_bf2(float a, float b) {
    return (unsigned)bf16_rne(a) | ((unsigned)bf16_rne(b) << 16);
}
static __device__ __forceinline__ unsigned cvt_pk_bf16(float a, float b) {
    unsigned r;
    asm("v_cvt_pk_bf16_f32 %0, %1, %2" : "=v"(r) : "v"(a), "v"(b));
    return r;
}
static __device__ __forceinline__ float bflo(unsigned u) { return __uint_as_float(u << 16); }
static __device__ __forceinline__ float bfhi(unsigned u) { return __uint_as_float(u & 0xFFFF0000u); }

union U4S8 { uint4 u; short8 s; };

// async global->LDS, 16B per lane; LDS dest = wave-uniform base + lane*16
static __device__ __forceinline__ void gll16(const ushort* g, ushort* l) {
    __builtin_amdgcn_global_load_lds(
        (const __attribute__((address_space(1))) unsigned int*)g,
        (__attribute__((address_space(3))) unsigned int*)l, 16, 0, 0);
}

// ---- pre-kernel: grid = 2304 (x transpose) + 72 (weight recast+swizzle) ----
__global__ __launch_bounds__(256)
void pre_kernel(const float* __restrict__ x, const float* __restrict__ w,
                ushort* __restrict__ xt, ushort* __restrict__ wt) {
    const int bid = blockIdx.x;
    const int tid = threadIdx.x;
    if (bid < 2304) {
        // transpose x[n][c][hw] fp32 -> xt[n][hw][c] bf16; tile 64c x 64hw
        __shared__ ushort t[64][68];
        const int n = bid / 288, rr = bid % 288;
        const int cblk = rr & 1, hw0 = (rr >> 1) * 64;
        #pragma unroll
        for (int j = 0; j < 4; ++j) {
            int item = j * 256 + tid;               // < 1024
            int c = item >> 4, q = item & 15;
            float4 f = *(const float4*)(x + ((size_t)(n * CI + cblk * 64 + c)) * P_TOT
                                        + hw0 + q * 4);
            t[q * 4 + 0][c] = bf16_rne(f.x);
            t[q * 4 + 1][c] = bf16_rne(f.y);
            t[q * 4 + 2][c] = bf16_rne(f.z);
            t[q * 4 + 3][c] = bf16_rne(f.w);
        }
        __syncthreads();
        #pragma unroll
        for (int j = 0; j < 4; ++j) {
            int item = j * 256 + tid;               // < 1024
            int row = item >> 4, seg = item & 15;
            uint2 v = *(const uint2*)&t[row][seg * 4];
            *(uint2*)(xt + ((size_t)n * P_TOT + hw0 + row) * CI + cblk * 64 + seg * 4) = v;
        }
    } else {
        // wt swizzled for LDS: slot s = k*2048 + o*16 + csw holds 8 ch of
        // c-seg cs = csw ^ (o&7); DMA's linear fill gives swizzled layout.
        int s = (bid - 2304) * 256 + tid;           // < 18432
        int k   = s >> 11;
        int r2  = s & 2047;
        int o   = r2 >> 4;
        int csw = r2 & 15;
        int cs  = csw ^ (o & 7);
        const float* src = w + (size_t)o * (CI * K2) + cs * 8 * K2 + k;
        ushort tmp[8];
        #pragma unroll
        for (int j = 0; j < 8; ++j) tmp[j] = bf16_rne(src[j * K2]);
        *(uint4*)&wt[(size_t)s * 8] = *(uint4*)tmp;
    }
}

__global__ __launch_bounds__(256, 2)
void dcn_mfma4_kernel(const ushort* __restrict__ xt,
                      const ushort* __restrict__ wt,
                      const float* __restrict__ offset,
                      const float* __restrict__ mask,
                      const float* __restrict__ bias,
                      float* __restrict__ out)
{
    __shared__ uint2  s_midx[K2 * TP];       // packed corner row indices
    __shared__ float4 s_mw[K2 * TP];         // bilinear*mask weights
    __shared__ ushort s_w[2][CO * CI];       // dbuf tap slab, swizzled, 2x32KB

    const int tid  = threadIdx.x;
    const int bid  = blockIdx.x;
    const int n    = bid & 7;                // XCD swizzle (n per XCD)
    const int tile = bid >> 3;               // 0..143
    const int ty   = tile / 6;               // 0..23 -> y0 = ty*4
    const int tx   = tile - ty * 6;          // 0..5  -> x0 = tx*16
    const int wave = tid >> 6;
    const int lane = tid & 63;
    const int l15  = lane & 15;
    const int quad = lane >> 4;
    // gather arrangement: pixel = lane>>2, 16B chunk = lane&3
    const int gp   = lane >> 2;
    const int gq   = lane & 3;
    // bpermute src lane for MFMA B-layout: g(l) = (l&15)*4 + (l>>4)
    const int permaddr = (l15 * 4 + quad) * 4;

    auto stage = [&](int k, int buf) {
        const ushort* g = wt + ((size_t)k * 2048 + wave * 512) * 8;
        ushort* l = &s_w[buf][wave * 512 * 8];
        #pragma unroll
        for (int i = 0; i < 8; ++i)
            gll16(g + (size_t)(i * 64 + lane) * 8, l + i * 64 * 8);
    };

    stage(0, 0);        // tap 0 in flight under meta phase

    // ---- meta phase (pixel i -> (iy,ix) within the 4x16 tile) ----
    for (int itm = 0; itm < 3; ++itm) {
        int item = itm * 256 + tid;          // k*TP + i, < 576
        if (item < K2 * TP) {
            int k = item / TP;
            int i = item % TP;
            int iy = i >> 4, ix = i & 15;
            int ph = ty * 4 + iy;
            int pw = tx * 16 + ix;
            int p  = ph * WI + pw;
            float offy = offset[((size_t)n * (2 * K2) + 2 * k    ) * P_TOT + p];
            float offx = offset[((size_t)n * (2 * K2) + 2 * k + 1) * P_TOT + p];
            float m    = mask  [((size_t)n * K2 + k) * P_TOT + p];
            int ky = k / 3, kx = k % 3;
            float py = (float)(ph - 1 + ky) + offy;
            float px = (float)(pw - 1 + kx) + offx;
            float y0f = floorf(py), x0f = floorf(px);
            float wy = py - y0f, wx = px - x0f;
            int y0 = (int)y0f, x0 = (int)x0f;
            int y1 = y0 + 1,  x1 = x0 + 1;
            bool vy0 = (y0 >= 0) && (y0 < HI);
            bool vy1 = (y1 >= 0) && (y1 < HI);
            bool vx0 = (x0 >= 0) && (x0 < WI);
            bool vx1 = (x1 >= 0) && (x1 < WI);
            unsigned i00 = (vy0 && vx0) ? (unsigned)(y0 * WI + x0) : 0u;
            unsigned i01 = (vy0 && vx1) ? (unsigned)(y0 * WI + x1) : 0u;
            unsigned i10 = (vy1 && vx0) ? (unsigned)(y1 * WI + x0) : 0u;
            unsigned i11 = (vy1 && vx1) ? (unsigned)(y1 * WI + x1) : 0u;
            float w00 = (vy0 && vx0) ? (1.f - wy) * (1.f - wx) * m : 0.f;
            float w01 = (vy0 && vx1) ? (1.f - wy) * wx          * m : 0.f;
            float w10 = (vy1 && vx0) ? wy * (1.f - wx)          * m : 0.f;
            float w11 = (vy1 && vx1) ? wy * wx                  * m : 0.f;
            s_midx[item] = make_uint2(i00 | (i01 << 16), i10 | (i11 << 16));
            s_mw[item]   = make_float4(w00, w01, w10, w11);
        }
    }
    __syncthreads();    // meta visible + tap0 slab landed (full drain, once)

    f32x4 acc[8];
    #pragma unroll
    for (int a = 0; a < 8; ++a) acc[a] = (f32x4){0.f, 0.f, 0.f, 0.f};

    // gather base: chunk gq of each 256B pixel row
    const ushort* xbg = xt + (size_t)n * (P_TOT * CI) + gq * 8;
    const int mrow_g = wave * 16 + gp;

    uint4 ga0[4], ga1[4], ga2[4], ga3[4];   // tap-A corner regs
    uint4 gb0[4], gb1[4], gb2[4], gb3[4];   // tap-B corner regs
    float4 mwa, mwb;

    // issue the 16 coalesced gathers + meta for tap k into a regset
    auto fetch = [&](int k, uint4 (&g0)[4], uint4 (&g1)[4],
                     uint4 (&g2)[4], uint4 (&g3)[4], float4& mw) {
        uint2 mi = s_midx[k * TP + mrow_g];
        mw = s_mw[k * TP + mrow_g];
        const ushort* c00 = xbg + (size_t)(mi.x & 0xFFFF) * CI;
        const ushort* c01 = xbg + (size_t)(mi.x >> 16)    * CI;
        const ushort* c10 = xbg + (size_t)(mi.y & 0xFFFF) * CI;
        const ushort* c11 = xbg + (size_t)(mi.y >> 16)    * CI;
        #pragma unroll
        for (int cb = 0; cb < 4; ++cb) {
            g0[cb] = *(const uint4*)(c00 + cb * 32);
            g1[cb] = *(const uint4*)(c01 + cb * 32);
            g2[cb] = *(const uint4*)(c10 + cb * 32);
            g3[cb] = *(const uint4*)(c11 + cb * 32);
        }
    };

    // bilinear + pack + bpermute + 8 MFMA for one tap held in a regset
    auto compute = [&](int buf, uint4 (&g0)[4], uint4 (&g1)[4],
                       uint4 (&g2)[4], uint4 (&g3)[4], float4 mw) {
        #pragma unroll
        for (int cb = 0; cb < 4; ++cb) {
            uint4 r0 = g0[cb], r1 = g1[cb], r2 = g2[cb], r3 = g3[cb];
            float v0 = mw.x * bflo(r0.x) + mw.y * bflo(r1.x) + mw.z * bflo(r2.x) + mw.w * bflo(r3.x);
            float v1 = mw.x * bfhi(r0.x) + mw.y * bfhi(r1.x) + mw.z * bfhi(r2.x) + mw.w * bfhi(r3.x);
            float v2 = mw.x * bflo(r0.y) + mw.y * bflo(r1.y) + mw.z * bflo(r2.y) + mw.w * bflo(r3.y);
            float v3 = mw.x * bfhi(r0.y) + mw.y * bfhi(r1.y) + mw.z * bfhi(r2.y) + mw.w * bfhi(r3.y);
            float v4 = mw.x * bflo(r0.z) + mw.y * bflo(r1.z) + mw.z * bflo(r2.z) + mw.w * bflo(r3.z);
            float v5 = mw.x * bfhi(r0.z) + mw.y * bfhi(r1.z) + mw.z * bfhi(r2.z) + mw.w * bfhi(r3.z);
            float v6 = mw.x * bflo(r0.w) + mw.y * bflo(r1.w) + mw.z * bflo(r2.w) + mw.w * bflo(r3.w);
            float v7 = mw.x * bfhi(r0.w) + mw.y * bfhi(r1.w) + mw.z * bfhi(r2.w) + mw.w * bfhi(r3.w);
            unsigned d0 = cvt_pk_bf16(v0, v1);
            unsigned d1 = cvt_pk_bf16(v2, v3);
            unsigned d2 = cvt_pk_bf16(v4, v5);
            unsigned d3 = cvt_pk_bf16(v6, v7);
            U4S8 cvt;
            cvt.u.x = (unsigned)__builtin_amdgcn_ds_bpermute(permaddr, (int)d0);
            cvt.u.y = (unsigned)__builtin_amdgcn_ds_bpermute(permaddr, (int)d1);
            cvt.u.z = (unsigned)__builtin_amdgcn_ds_bpermute(permaddr, (int)d2);
            cvt.u.w = (unsigned)__builtin_amdgcn_ds_bpermute(permaddr, (int)d3);
            short8 bfr = cvt.s;
            __builtin_amdgcn_s_setprio(1);
            #pragma unroll
            for (int ot = 0; ot < 8; ++ot) {
                int o = ot * 16 + l15;
                short8 afr = *(const short8*)&s_w[buf][o * CI + (((cb * 4 + quad) ^ (o & 7)) * 8)];
                acc[ot] = __builtin_amdgcn_mfma_f32_16x16x32_bf16(afr, bfr, acc[ot], 0, 0, 0);
            }
            __builtin_amdgcn_s_setprio(0);
        }
    };

    fetch(0, ga0, ga1, ga2, ga3, mwa);      // tap 0 gathers in flight

    for (int kk = 0; kk < 4; ++kk) {
        const int k = 2 * kk;
        // ---- first half: compute tap k (A), prefetch tap k+1 (B) ----
        stage(k + 1, 1);                    // oldest new VMEM: 8 DMAs
        fetch(k + 1, gb0, gb1, gb2, gb3, mwb);
        compute(0, ga0, ga1, ga2, ga3, mwa);
        // drain ONLY the stage DMAs (oldest 8); k+1 gathers stay in flight
        asm volatile("s_waitcnt vmcnt(16)" ::: "memory");
        __builtin_amdgcn_s_barrier();
        // ---- second half: compute tap k+1 (B), prefetch tap k+2 (A) ----
        stage(k + 2, 0);
        fetch(k + 2, ga0, ga1, ga2, ga3, mwa);
        compute(1, gb0, gb1, gb2, gb3, mwb);
        asm volatile("s_waitcnt vmcnt(16)" ::: "memory");
        __builtin_amdgcn_s_barrier();
    }
    compute(0, ga0, ga1, ga2, ga3, mwa);    // tap 8 (slab landed, no prefetch)

    // ---- epilogue (wave = iy row of the 4x16 tile, l15 = ix) ----
    const int pbase = (ty * 4 + wave) * WI + tx * 16 + l15;
    #pragma unroll
    for (int ot = 0; ot < 8; ++ot) {
        #pragma unroll
        for (int r = 0; r < 4; ++r) {
            int o = ot * 16 + quad * 4 + r;
            out[((size_t)n * CO + o) * P_TOT + pbase] = acc[ot][r] + bias[o];
        }
    }
}

// ---------------- fallback (no workspace): round-2 structure ----------------
__global__ __launch_bounds__(256, 3)
void dcn_fallback_kernel(const float* __restrict__ x,
                         const float* __restrict__ offset,
                         const float* __restrict__ mask,
                         const float* __restrict__ weight,
                         const float* __restrict__ bias,
                         float* __restrict__ out)
{
    __shared__ uint2  s_midx[K2 * TP];
    __shared__ float4 s_mw[K2 * TP];
    __shared__ ushort s_v[TP * CPAD];
    __shared__ ushort s_w[CO * CPAD];

    const int tid  = threadIdx.x;
    const int bid  = blockIdx.x;
    const int n    = bid & 7;
    const int p0   = (bid >> 3) * TP;

    for (int it = 0; it < 3; ++it) {
        int item = it * 256 + tid;
        if (item < K2 * TP) {
            int k = item / TP;
            int i = item % TP;
            int p  = p0 + i;
            int ph = p / WI;
            int pw = p % WI;
            float offy = offset[((size_t)n * (2 * K2) + 2 * k    ) * P_TOT + p];
            float offx = offset[((size_t)n * (2 * K2) + 2 * k + 1) * P_TOT + p];
            float m    = mask  [((size_t)n * K2 + k) * P_TOT + p];
            int ky = k / 3, kx = k % 3;
            float py = (float)(ph - 1 + ky) + offy;
            float px = (float)(pw - 1 + kx) + offx;
            float y0f = floorf(py), x0f = floorf(px);
            float wy = py - y0f, wx = px - x0f;
            int y0 = (int)y0f, x0 = (int)x0f;
            int y1 = y0 + 1,  x1 = x0 + 1;
            bool vy0 = (y0 >= 0) && (y0 < HI);
            bool vy1 = (y1 >= 0) && (y1 < HI);
            bool vx0 = (x0 >= 0) && (x0 < WI);
            bool vx1 = (x1 >= 0) && (x1 < WI);
            unsigned i00 = (vy0 && vx0) ? (unsigned)(y0 * WI + x0) : 0u;
            unsigned i01 = (vy0 && vx1) ? (unsigned)(y0 * WI + x1) : 0u;
            unsigned i10 = (vy1 && vx0) ? (unsigned)(y1 * WI + x0) : 0u;
            unsigned i11 = (vy1 && vx1) ? (unsigned)(y1 * WI + x1) : 0u;
            float w00 = (vy0 && vx0) ? (1.f - wy) * (1.f - wx) * m : 0.f;
            float w01 = (vy0 && vx1) ? (1.f - wy) * wx          * m : 0.f;
            float w10 = (vy1 && vx0) ? wy * (1.f - wx)          * m : 0.f;
            float w11 = (vy1 && vx1) ? wy * wx                  * m : 0.f;
            s_midx[item] = make_uint2(i00 | (i01 << 16), i10 | (i11 << 16));
            s_mw[item]   = make_float4(w00, w01, w10, w11);
        }
    }
    __syncthreads();

    const int wave = tid >> 6;
    const int lane = tid & 63;
    const int l15  = lane & 15;
    const int quad = lane >> 4;
    const int o_base = (wave >> 1) * 64;
    const int p_base = (wave & 1) * 32;
    const int gp = tid & 63;
    const int cg = wave;

    f32x4 acc[4][2];
    #pragma unroll
    for (int a = 0; a < 4; ++a)
        #pragma unroll
        for (int b = 0; b < 2; ++b) acc[a][b] = (f32x4){0.f, 0.f, 0.f, 0.f};

    for (int cb = 0; cb < 4; ++cb) {
        for (int k = 0; k < K2; ++k) {
            {
                uint2  mi = s_midx[k * TP + gp];
                float4 mw = s_mw[k * TP + gp];
                int i00 = mi.x & 0xFFFF, i01 = mi.x >> 16;
                int i10 = mi.y & 0xFFFF, i11 = mi.y >> 16;
                const float* xb = x + ((size_t)(n * CI + cb * 32 + cg * 8)) * (HI * WI);
                float v[8];
                #pragma unroll
                for (int j = 0; j < 8; ++j) {
                    const float* xp = xb + (size_t)j * (HI * WI);
                    v[j] = mw.x * xp[i00] + mw.y * xp[i01]
                         + mw.z * xp[i10] + mw.w * xp[i11];
                }
                uint4 pk;
                pk.x = pack_bf2(v[0], v[1]);
                pk.y = pack_bf2(v[2], v[3]);
                pk.z = pack_bf2(v[4], v[5]);
                pk.w = pack_bf2(v[6], v[7]);
                *(uint4*)&s_v[gp * CPAD + cg * 8] = pk;
            }
            {
                int o = tid >> 1, half = tid & 1;
                const float* wsrc = weight + (size_t)o * (CI * K2)
                                  + (cb * 32 + half * 16) * K2 + k;
                ushort tmp[16];
                #pragma unroll
                for (int i = 0; i < 16; ++i) tmp[i] = bf16_rne(wsrc[i * K2]);
                *(uint4*)&s_w[o * CPAD + half * 16]     = *(uint4*)&tmp[0];
                *(uint4*)&s_w[o * CPAD + half * 16 + 8] = *(uint4*)&tmp[8];
            }
            __syncthreads();
            short8 afr[4], bfr[2];
            #pragma unroll
            for (int ot = 0; ot < 4; ++ot)
                afr[ot] = *(const short8*)&s_w[(o_base + ot * 16 + l15) * CPAD + quad * 8];
            #pragma unroll
            for (int pt = 0; pt < 2; ++pt)
                bfr[pt] = *(const short8*)&s_v[(p_base + pt * 16 + l15) * CPAD + quad * 8];
            #pragma unroll
            for (int ot = 0; ot < 4; ++ot)
                #pragma unroll
                for (int pt = 0; pt < 2; ++pt)
                    acc[ot][pt] = __builtin_amdgcn_mfma_f32_16x16x32_bf16(
                        afr[ot], bfr[pt], acc[ot][pt], 0, 0, 0);
            __syncthreads();
        }
    }

    #pragma unroll
    for (int ot = 0; ot < 4; ++ot)
        #pragma unroll
        for (int r = 0; r < 4; ++r) {
            int o = o_base + ot * 16 + quad * 4 + r;
            float b = bias[o];
            #pragma unroll
            for (int pt = 0; pt < 2; ++pt) {
                int p = p0 + p_base + pt * 16 + l15;
                out[((size_t)n * CO + o) * P_TOT + p] = acc[ot][pt][r] + b;
            }
        }
}

extern "C" void kernel_launch(void* const* d_in, const int* in_sizes, int n_in,
                              void* d_out, int out_size, void* d_ws, size_t ws_size,
                              hipStream_t stream) {
    const float* x      = (const float*)d_in[0];
    const float* offset = (const float*)d_in[1];
    const float* mask   = (const float*)d_in[2];
    const float* weight = (const float*)d_in[3];
    const float* bias   = (const float*)d_in[4];
    float* out = (float*)d_out;

    dim3 block(256);
    if (ws_size >= WS_NEED) {
        ushort* xt = (ushort*)d_ws;
        ushort* wt = xt + XT_ELEMS;
        pre_kernel<<<dim3(2304 + 72), block, 0, stream>>>(x, weight, xt, wt);
        dcn_mfma4_kernel<<<dim3(NI * NTILE), block, 0, stream>>>(
            xt, wt, offset, mask, bias, out);
    } else {
        dcn_fallback_kernel<<<dim3(NI * NTILE), block, 0, stream>>>(
            x, offset, mask, weight, bias, out);
    }
}

// Round 11
// 161.692 us; speedup vs baseline: 2.9185x; 1.0255x over previous
//
#include <hip/hip_runtime.h>

// DCNv2 fused v13 = v10 + (a) chunk-planar xt => gather lands DIRECTLY in
// MFMA B-layout (deletes 16 ds_bpermute/tap) + (b) single-buffer weight
// slab => 46.6KB LDS => 3 blocks/CU (was 2). Diagnosis from v12-null: no
// pipe >55% busy, latency-bound at 2 waves/SIMD; raise TLP + shorten chain.
// xt[n][chunk][hw][8ch]: lane(l15=pixel, quad) reads plane cb*4+quad at its
// corner row -> 16-lane group = 16x16B at mostly-consecutive rows (~4-8
// line-trans, per r8-validated TA model). Single-buffer ledger per tap:
// compute(k) -> s_barrier (afr reads already consumed via lgkm) ->
// stage(k+1) -> fetch(k+1) -> vmcnt(16) (drain 8 DMAs, keep 16 gathers
// in flight) -> s_barrier. sched_barrier(0) pins stage-before-fetch order.

#define NI 8
#define CI 128
#define HI 96
#define WI 96
#define CO 128
#define K2 9
#define P_TOT 9216
#define TP 64
#define NTILE 144                                   // 24 ty * 6 tx
#define CPAD 40
#define XT_ELEMS ((size_t)NI * P_TOT * CI)          // 9,437,184 bf16
#define WT_ELEMS ((size_t)K2 * CO * CI)             // 147,456 bf16
#define WS_NEED ((XT_ELEMS + WT_ELEMS) * 2)
#define PLANE ((size_t)P_TOT * 8)                   // ushorts per chunk-plane

typedef short short8 __attribute__((ext_vector_type(8)));
typedef float f32x4 __attribute__((ext_vector_type(4)));

static __device__ __forceinline__ ushort bf16_rne(float x) {
    unsigned u = __float_as_uint(x);
    u = (u + 0x7FFF + ((u >> 16) & 1)) >> 16;
    return (ushort)u;
}
static __device__ __forceinline__ unsigned pack_bf2(float a, float b) {
    return (unsigned)bf16_rne(a) | ((unsigned)bf16_rne(b) << 16);
}
static __device__ __forceinline__ unsigned cvt_pk_bf16(float a, float b) {
    unsigned r;
    asm("v_cvt_pk_bf16_f32 %0, %1, %2" : "=v"(r) : "v"(a), "v"(b));
    return r;
}
static __device__ __forceinline__ float bflo(unsigned u) { return __uint_as_float(u << 16); }
static __device__ __forceinline__ float bfhi(unsigned u) { return __uint_as_float(u & 0xFFFF0000u); }

union U4S8 { uint4 u; short8 s; };

// async global->LDS, 16B per lane; LDS dest = wave-uniform base + lane*16
static __device__ __forceinline__ void gll16(const ushort* g, ushort* l) {
    __builtin_amdgcn_global_load_lds(
        (const __attribute__((address_space(1))) unsigned int*)g,
        (__attribute__((address_space(3))) unsigned int*)l, 16, 0, 0);
}

// ---- pre-kernel: grid = 2304 (x transpose) + 72 (weight recast+swizzle) ----
__global__ __launch_bounds__(256)
void pre_kernel(const float* __restrict__ x, const float* __restrict__ w,
                ushort* __restrict__ xt, ushort* __restrict__ wt) {
    const int bid = blockIdx.x;
    const int tid = threadIdx.x;
    if (bid < 2304) {
        // transpose x[n][c][hw] fp32 -> xt[n][chunk(16)][hw][8ch] bf16
        __shared__ ushort t[64][68];
        const int n = bid / 288, rr = bid % 288;
        const int cblk = rr & 1, hw0 = (rr >> 1) * 64;
        #pragma unroll
        for (int j = 0; j < 4; ++j) {
            int item = j * 256 + tid;               // < 1024
            int c = item >> 4, q = item & 15;
            float4 f = *(const float4*)(x + ((size_t)(n * CI + cblk * 64 + c)) * P_TOT
                                        + hw0 + q * 4);
            t[q * 4 + 0][c] = bf16_rne(f.x);
            t[q * 4 + 1][c] = bf16_rne(f.y);
            t[q * 4 + 2][c] = bf16_rne(f.z);
            t[q * 4 + 3][c] = bf16_rne(f.w);
        }
        __syncthreads();
        #pragma unroll
        for (int j = 0; j < 4; ++j) {
            int item = j * 256 + tid;               // < 1024
            int row = item >> 4, seg = item & 15;   // seg = 4-ch group
            uint2 v = *(const uint2*)&t[row][seg * 4];
            int chunk = cblk * 8 + (seg >> 1);      // 8-ch plane index
            int sub   = (seg & 1) * 4;
            *(uint2*)(xt + ((size_t)n * 16 + chunk) * PLANE
                         + (size_t)(hw0 + row) * 8 + sub) = v;
        }
    } else {
        // wt swizzled for LDS: slot s = k*2048 + o*16 + csw holds 8 ch of
        // c-seg cs = csw ^ (o&7); DMA's linear fill gives swizzled layout.
        int s = (bid - 2304) * 256 + tid;           // < 18432
        int k   = s >> 11;
        int r2  = s & 2047;
        int o   = r2 >> 4;
        int csw = r2 & 15;
        int cs  = csw ^ (o & 7);
        const float* src = w + (size_t)o * (CI * K2) + cs * 8 * K2 + k;
        ushort tmp[8];
        #pragma unroll
        for (int j = 0; j < 8; ++j) tmp[j] = bf16_rne(src[j * K2]);
        *(uint4*)&wt[(size_t)s * 8] = *(uint4*)tmp;
    }
}

__global__ __launch_bounds__(256, 3)
void dcn_mfma4_kernel(const ushort* __restrict__ xt,
                      const ushort* __restrict__ wt,
                      const float* __restrict__ offset,
                      const float* __restrict__ mask,
                      const float* __restrict__ bias,
                      float* __restrict__ out)
{
    __shared__ uint2  s_midx[K2 * TP];       // packed corner row indices
    __shared__ float4 s_mw[K2 * TP];         // bilinear*mask weights
    __shared__ ushort s_w[CO * CI];          // SINGLE tap slab, swizzled, 32KB

    const int tid  = threadIdx.x;
    const int bid  = blockIdx.x;
    const int n    = bid & 7;                // XCD swizzle (n per XCD)
    const int tile = bid >> 3;               // 0..143
    const int ty   = tile / 6;               // 0..23 -> y0 = ty*4
    const int tx   = tile - ty * 6;          // 0..5  -> x0 = tx*16
    const int wave = tid >> 6;
    const int lane = tid & 63;
    const int l15  = lane & 15;              // pixel within wave row
    const int quad = lane >> 4;              // k-chunk within cb

    auto stage = [&](int k) {
        const ushort* g = wt + ((size_t)k * 2048 + wave * 512) * 8;
        ushort* l = &s_w[wave * 512 * 8];
        #pragma unroll
        for (int i = 0; i < 8; ++i)
            gll16(g + (size_t)(i * 64 + lane) * 8, l + i * 64 * 8);
    };

    stage(0);           // tap 0 in flight under meta phase

    // ---- meta phase (pixel i -> (iy,ix) within the 4x16 tile) ----
    for (int itm = 0; itm < 3; ++itm) {
        int item = itm * 256 + tid;          // k*TP + i, < 576
        if (item < K2 * TP) {
            int k = item / TP;
            int i = item % TP;
            int iy = i >> 4, ix = i & 15;
            int ph = ty * 4 + iy;
            int pw = tx * 16 + ix;
            int p  = ph * WI + pw;
            float offy = offset[((size_t)n * (2 * K2) + 2 * k    ) * P_TOT + p];
            float offx = offset[((size_t)n * (2 * K2) + 2 * k + 1) * P_TOT + p];
            float m    = mask  [((size_t)n * K2 + k) * P_TOT + p];
            int ky = k / 3, kx = k % 3;
            float py = (float)(ph - 1 + ky) + offy;
            float px = (float)(pw - 1 + kx) + offx;
            float y0f = floorf(py), x0f = floorf(px);
            float wy = py - y0f, wx = px - x0f;
            int y0 = (int)y0f, x0 = (int)x0f;
            int y1 = y0 + 1,  x1 = x0 + 1;
            bool vy0 = (y0 >= 0) && (y0 < HI);
            bool vy1 = (y1 >= 0) && (y1 < HI);
            bool vx0 = (x0 >= 0) && (x0 < WI);
            bool vx1 = (x1 >= 0) && (x1 < WI);
            unsigned i00 = (vy0 && vx0) ? (unsigned)(y0 * WI + x0) : 0u;
            unsigned i01 = (vy0 && vx1) ? (unsigned)(y0 * WI + x1) : 0u;
            unsigned i10 = (vy1 && vx0) ? (unsigned)(y1 * WI + x0) : 0u;
            unsigned i11 = (vy1 && vx1) ? (unsigned)(y1 * WI + x1) : 0u;
            float w00 = (vy0 && vx0) ? (1.f - wy) * (1.f - wx) * m : 0.f;
            float w01 = (vy0 && vx1) ? (1.f - wy) * wx          * m : 0.f;
            float w10 = (vy1 && vx0) ? wy * (1.f - wx)          * m : 0.f;
            float w11 = (vy1 && vx1) ? wy * wx                  * m : 0.f;
            s_midx[item] = make_uint2(i00 | (i01 << 16), i10 | (i11 << 16));
            s_mw[item]   = make_float4(w00, w01, w10, w11);
        }
    }
    __syncthreads();    // meta visible + tap0 slab landed (full drain, once)

    f32x4 acc[8];
    #pragma unroll
    for (int a = 0; a < 8; ++a) acc[a] = (f32x4){0.f, 0.f, 0.f, 0.f};

    // chunk-plane base for this lane: plane quad of n; cb adds 4 planes
    const ushort* xp = xt + ((size_t)n * 16 + quad) * PLANE;
    const int mrow = wave * 16 + l15;        // meta row = this lane's pixel

    uint4 g0[4], g1[4], g2[4], g3[4];
    float4 mwc;

    // 16 gathers for tap k: lane reads 16B (8 ch of plane cb*4+quad) at its
    // pixel's corner row -> B-frag layout directly (col=l15, k=quad*8+j)
    auto fetch = [&](int k) {
        uint2 mi = s_midx[k * TP + mrow];
        mwc = s_mw[k * TP + mrow];
        size_t r00 = (size_t)(mi.x & 0xFFFF) * 8;
        size_t r01 = (size_t)(mi.x >> 16)    * 8;
        size_t r10 = (size_t)(mi.y & 0xFFFF) * 8;
        size_t r11 = (size_t)(mi.y >> 16)    * 8;
        #pragma unroll
        for (int cb = 0; cb < 4; ++cb) {
            const ushort* pb = xp + (size_t)cb * 4 * PLANE;
            g0[cb] = *(const uint4*)(pb + r00);
            g1[cb] = *(const uint4*)(pb + r01);
            g2[cb] = *(const uint4*)(pb + r10);
            g3[cb] = *(const uint4*)(pb + r11);
        }
    };

    auto compute = [&]() {
        #pragma unroll
        for (int cb = 0; cb < 4; ++cb) {
            uint4 r0 = g0[cb], r1 = g1[cb], r2 = g2[cb], r3 = g3[cb];
            float v0 = mwc.x * bflo(r0.x) + mwc.y * bflo(r1.x) + mwc.z * bflo(r2.x) + mwc.w * bflo(r3.x);
            float v1 = mwc.x * bfhi(r0.x) + mwc.y * bfhi(r1.x) + mwc.z * bfhi(r2.x) + mwc.w * bfhi(r3.x);
            float v2 = mwc.x * bflo(r0.y) + mwc.y * bflo(r1.y) + mwc.z * bflo(r2.y) + mwc.w * bflo(r3.y);
            float v3 = mwc.x * bfhi(r0.y) + mwc.y * bfhi(r1.y) + mwc.z * bfhi(r2.y) + mwc.w * bfhi(r3.y);
            float v4 = mwc.x * bflo(r0.z) + mwc.y * bflo(r1.z) + mwc.z * bflo(r2.z) + mwc.w * bflo(r3.z);
            float v5 = mwc.x * bfhi(r0.z) + mwc.y * bfhi(r1.z) + mwc.z * bfhi(r2.z) + mwc.w * bfhi(r3.z);
            float v6 = mwc.x * bflo(r0.w) + mwc.y * bflo(r1.w) + mwc.z * bflo(r2.w) + mwc.w * bflo(r3.w);
            float v7 = mwc.x * bfhi(r0.w) + mwc.y * bfhi(r1.w) + mwc.z * bfhi(r2.w) + mwc.w * bfhi(r3.w);
            U4S8 cvt;
            cvt.u.x = cvt_pk_bf16(v0, v1);   // already MFMA B-frag layout
            cvt.u.y = cvt_pk_bf16(v2, v3);
            cvt.u.z = cvt_pk_bf16(v4, v5);
            cvt.u.w = cvt_pk_bf16(v6, v7);
            short8 bfr = cvt.s;
            __builtin_amdgcn_s_setprio(1);
            #pragma unroll
            for (int ot = 0; ot < 8; ++ot) {
                int o = ot * 16 + l15;
                short8 afr = *(const short8*)&s_w[o * CI + (((cb * 4 + quad) ^ (o & 7)) * 8)];
                acc[ot] = __builtin_amdgcn_mfma_f32_16x16x32_bf16(afr, bfr, acc[ot], 0, 0, 0);
            }
            __builtin_amdgcn_s_setprio(0);
        }
    };

    fetch(0);                                // tap-0 gathers in flight

    for (int k = 0; k < K2; ++k) {
        compute();                           // slab k + gathers k
        if (k < 8) {
            __builtin_amdgcn_s_barrier();    // all waves done reading slab k
            stage(k + 1);                    // 8 DMAs (oldest new VMEM)
            __builtin_amdgcn_sched_barrier(0);
            fetch(k + 1);                    // 16 gathers (newer)
            __builtin_amdgcn_sched_barrier(0);
            asm volatile("s_waitcnt vmcnt(16)" ::: "memory");  // DMAs landed
            __builtin_amdgcn_sched_barrier(0);
            __builtin_amdgcn_s_barrier();    // every wave's DMA landed
        }
    }

    // ---- epilogue (wave = iy row of the 4x16 tile, l15 = ix) ----
    const int pbase = (ty * 4 + wave) * WI + tx * 16 + l15;
    #pragma unroll
    for (int ot = 0; ot < 8; ++ot) {
        #pragma unroll
        for (int r = 0; r < 4; ++r) {
            int o = ot * 16 + quad * 4 + r;
            out[((size_t)n * CO + o) * P_TOT + pbase] = acc[ot][r] + bias[o];
        }
    }
}

// ---------------- fallback (no workspace): round-2 structure ----------------
__global__ __launch_bounds__(256, 3)
void dcn_fallback_kernel(const float* __restrict__ x,
                         const float* __restrict__ offset,
                         const float* __restrict__ mask,
                         const float* __restrict__ weight,
                         const float* __restrict__ bias,
                         float* __restrict__ out)
{
    __shared__ uint2  s_midx[K2 * TP];
    __shared__ float4 s_mw[K2 * TP];
    __shared__ ushort s_v[TP * CPAD];
    __shared__ ushort s_w[CO * CPAD];

    const int tid  = threadIdx.x;
    const int bid  = blockIdx.x;
    const int n    = bid & 7;
    const int p0   = (bid >> 3) * TP;

    for (int it = 0; it < 3; ++it) {
        int item = it * 256 + tid;
        if (item < K2 * TP) {
            int k = item / TP;
            int i = item % TP;
            int p  = p0 + i;
            int ph = p / WI;
            int pw = p % WI;
            float offy = offset[((size_t)n * (2 * K2) + 2 * k    ) * P_TOT + p];
            float offx = offset[((size_t)n * (2 * K2) + 2 * k + 1) * P_TOT + p];
            float m    = mask  [((size_t)n * K2 + k) * P_TOT + p];
            int ky = k / 3, kx = k % 3;
            float py = (float)(ph - 1 + ky) + offy;
            float px = (float)(pw - 1 + kx) + offx;
            float y0f = floorf(py), x0f = floorf(px);
            float wy = py - y0f, wx = px - x0f;
            int y0 = (int)y0f, x0 = (int)x0f;
            int y1 = y0 + 1,  x1 = x0 + 1;
            bool vy0 = (y0 >= 0) && (y0 < HI);
            bool vy1 = (y1 >= 0) && (y1 < HI);
            bool vx0 = (x0 >= 0) && (x0 < WI);
            bool vx1 = (x1 >= 0) && (x1 < WI);
            unsigned i00 = (vy0 && vx0) ? (unsigned)(y0 * WI + x0) : 0u;
            unsigned i01 = (vy0 && vx1) ? (unsigned)(y0 * WI + x1) : 0u;
            unsigned i10 = (vy1 && vx0) ? (unsigned)(y1 * WI + x0) : 0u;
            unsigned i11 = (vy1 && vx1) ? (unsigned)(y1 * WI + x1) : 0u;
            float w00 = (vy0 && vx0) ? (1.f - wy) * (1.f - wx) * m : 0.f;
            float w01 = (vy0 && vx1) ? (1.f - wy) * wx          * m : 0.f;
            float w10 = (vy1 && vx0) ? wy * (1.f - wx)          * m : 0.f;
            float w11 = (vy1 && vx1) ? wy * wx                  * m : 0.f;
            s_midx[item] = make_uint2(i00 | (i01 << 16), i10 | (i11 << 16));
            s_mw[item]   = make_float4(w00, w01, w10, w11);
        }
    }
    __syncthreads();

    const int wave = tid >> 6;
    const int lane = tid & 63;
    const int l15  = lane & 15;
    const int quad = lane >> 4;
    const int o_base = (wave >> 1) * 64;
    const int p_base = (wave & 1) * 32;
    const int gp = tid & 63;
    const int cg = wave;

    f32x4 acc[4][2];
    #pragma unroll
    for (int a = 0; a < 4; ++a)
        #pragma unroll
        for (int b = 0; b < 2; ++b) acc[a][b] = (f32x4){0.f, 0.f, 0.f, 0.f};

    for (int cb = 0; cb < 4; ++cb) {
        for (int k = 0; k < K2; ++k) {
            {
                uint2  mi = s_midx[k * TP + gp];
                float4 mw = s_mw[k * TP + gp];
                int i00 = mi.x & 0xFFFF, i01 = mi.x >> 16;
                int i10 = mi.y & 0xFFFF, i11 = mi.y >> 16;
                const float* xb = x + ((size_t)(n * CI + cb * 32 + cg * 8)) * (HI * WI);
                float v[8];
                #pragma unroll
                for (int j = 0; j < 8; ++j) {
                    const float* xp = xb + (size_t)j * (HI * WI);
                    v[j] = mw.x * xp[i00] + mw.y * xp[i01]
                         + mw.z * xp[i10] + mw.w * xp[i11];
                }
                uint4 pk;
                pk.x = pack_bf2(v[0], v[1]);
                pk.y = pack_bf2(v[2], v[3]);
                pk.z = pack_bf2(v[4], v[5]);
                pk.w = pack_bf2(v[6], v[7]);
                *(uint4*)&s_v[gp * CPAD + cg * 8] = pk;
            }
            {
                int o = tid >> 1, half = tid & 1;
                const float* wsrc = weight + (size_t)o * (CI * K2)
                                  + (cb * 32 + half * 16) * K2 + k;
                ushort tmp[16];
                #pragma unroll
                for (int i = 0; i < 16; ++i) tmp[i] = bf16_rne(wsrc[i * K2]);
                *(uint4*)&s_w[o * CPAD + half * 16]     = *(uint4*)&tmp[0];
                *(uint4*)&s_w[o * CPAD + half * 16 + 8] = *(uint4*)&tmp[8];
            }
            __syncthreads();
            short8 afr[4], bfr[2];
            #pragma unroll
            for (int ot = 0; ot < 4; ++ot)
                afr[ot] = *(const short8*)&s_w[(o_base + ot * 16 + l15) * CPAD + quad * 8];
            #pragma unroll
            for (int pt = 0; pt < 2; ++pt)
                bfr[pt] = *(const short8*)&s_v[(p_base + pt * 16 + l15) * CPAD + quad * 8];
            #pragma unroll
            for (int ot = 0; ot < 4; ++ot)
                #pragma unroll
                for (int pt = 0; pt < 2; ++pt)
                    acc[ot][pt] = __builtin_amdgcn_mfma_f32_16x16x32_bf16(
                        afr[ot], bfr[pt], acc[ot][pt], 0, 0, 0);
            __syncthreads();
        }
    }

    #pragma unroll
    for (int ot = 0; ot < 4; ++ot)
        #pragma unroll
        for (int r = 0; r < 4; ++r) {
            int o = o_base + ot * 16 + quad * 4 + r;
            float b = bias[o];
            #pragma unroll
            for (int pt = 0; pt < 2; ++pt) {
                int p = p0 + p_base + pt * 16 + l15;
                out[((size_t)n * CO + o) * P_TOT + p] = acc[ot][pt][r] + b;
            }
        }
}

extern "C" void kernel_launch(void* const* d_in, const int* in_sizes, int n_in,
                              void* d_out, int out_size, void* d_ws, size_t ws_size,
                              hipStream_t stream) {
    const float* x      = (const float*)d_in[0];
    const float* offset = (const float*)d_in[1];
    const float* mask   = (const float*)d_in[2];
    const float* weight = (const float*)d_in[3];
    const float* bias   = (const float*)d_in[4];
    float* out = (float*)d_out;

    dim3 block(256);
    if (ws_size >= WS_NEED) {
        ushort* xt = (ushort*)d_ws;
        ushort* wt = xt + XT_ELEMS;
        pre_kernel<<<dim3(2304 + 72), block, 0, stream>>>(x, weight, xt, wt);
        dcn_mfma4_kernel<<<dim3(NI * NTILE), block, 0, stream>>>(
            xt, wt, offset, mask, bias, out);
    } else {
        dcn_fallback_kernel<<<dim3(NI * NTILE), block, 0, stream>>>(
            x, offset, mask, weight, bias, out);
    }
}